// Round 1
// baseline (66.428 us; speedup 1.0000x reference)
//
#include <hip/hip_runtime.h>

// Problem constants (from reference): V=16, T=2048, D=1, K=16
#define NV 16
#define NT 2048
#define NK 16

// One thread per output row i in [K, T). Timestamps for video v staged in LDS.
// Since t is sorted along T and D==1, score -(t_i - t_j)^2 is nondecreasing in
// j for j < i; top-k = last-k window, with jax.lax.top_k stable-tie semantics:
// equal values ordered by ascending index, boundary tie-group truncated to its
// lowest indices. Ties in score occur iff t_j values are bit-equal (subtraction
// is exact here; squaring is injective on distinct diffs for this value range).
__global__ __launch_bounds__(256) void topk_rows_kernel(
    const float* __restrict__ t,      // (V, T, 1) float32, sorted along T
    const int* __restrict__ mask,     // (V, T, 1) bool->int32 prefix mask
    int* __restrict__ out)            // (V, T-K, K) int32
{
    __shared__ float ts[NT];

    const int blocks_per_v = (NT - NK + 255) / 256;   // 8
    const int v = blockIdx.x / blocks_per_v;
    const int b = blockIdx.x % blocks_per_v;

    // Stage this video's timestamps into LDS (2048 floats = 8 KB).
    for (int j = threadIdx.x; j < NT; j += 256)
        ts[j] = t[v * NT + j];
    __syncthreads();

    const int i = NK + b * 256 + (int)threadIdx.x;
    if (i >= NT) return;

    int* orow = out + ((size_t)v * (NT - NK) + (i - NK)) * NK;

    // valid iff i < seq_len[v] iff mask[v][i] nonzero (mask is the prefix mask)
    if (mask[v * NT + i] == 0) {
        #pragma unroll
        for (int s = 0; s < NK; ++s) orow[s] = 0;
        return;
    }

    int res[NK];
    int slot = 0;
    int j = i - 1;
    // Walk backward over runs of equal timestamps. Each run is one tie-group:
    // emit ascending indices within the group; truncate final group to its
    // lowest indices (stable top_k semantics).
    while (slot < NK && j >= 0) {
        const float val = ts[j];
        int p = j;
        while (p > 0 && ts[p - 1] == val) --p;
        const int run = j - p + 1;
        const int take = (run < NK - slot) ? run : (NK - slot);
        for (int r = 0; r < take; ++r) res[slot + r] = p + r;
        slot += take;
        j = p - 1;
    }
    // i >= K guarantees >= K candidates, so slot == K here; guard anyway.
    for (; slot < NK; ++slot) res[slot] = 0;

    #pragma unroll
    for (int s = 0; s < NK; ++s) orow[s] = res[s];
}

extern "C" void kernel_launch(void* const* d_in, const int* in_sizes, int n_in,
                              void* d_out, int out_size, void* d_ws, size_t ws_size,
                              hipStream_t stream) {
    const float* t    = (const float*)d_in[0];   // (V,T,1) float32
    const int*   mask = (const int*)d_in[1];     // (V,T,1) bool (int32 on device)
    // d_in[2] is k == 16, compile-time constant here.
    int* out = (int*)d_out;                      // (V, T-K, K) int32

    const int blocks_per_v = (NT - NK + 255) / 256;  // 8
    topk_rows_kernel<<<dim3(NV * blocks_per_v), dim3(256), 0, stream>>>(t, mask, out);
}